// Round 5
// baseline (1087.759 us; speedup 1.0000x reference)
//
#include <hip/hip_runtime.h>

#define CRF_B 256
#define CRF_S 1024
#define CRF_T 128
#define GSPLIT 8                     // gold: S-slices per batch (128 rows each)
#define NFWD   CRF_B                 // fused grid: blocks [0,256) = fwd chains
#define NGOLD  (CRF_B * GSPLIT)      //             blocks [256, 2304) = gold
#define WS_FWD (CRF_B * GSPLIT)      // ws: [0,2048) gold partials,
#define WS_N   (WS_FWD + CRF_B)      //     [2048,2304) fwd results

typedef __attribute__((ext_vector_type(4))) float f32x4;

// Wait for LDS ops only (no s_barrier anywhere in the fwd chain: single wave).
__device__ __forceinline__ void wait_lds() {
    __asm__ volatile("s_waitcnt lgkmcnt(0)" ::: "memory");
}

// x + x[lane^32] in ALL lanes, via v_permlane32_swap (VALU pipe, no LDS).
// With both operands = x: new_vdst[i<32]=x[i+32], new_vdst[i>=32]=x[i];
// new_vsrc[i<32]=x[i],   new_vsrc[i>=32]=x[i-32]  -> sum = cross-half sum.
__device__ __forceinline__ float xhalf_sum(float x) {
    int xi = __float_as_int(x);
    auto r = __builtin_amdgcn_permlane32_swap(xi, xi, false, false);
    return __int_as_float(r[0]) + __int_as_float(r[1]);
}

// DPP quad butterflies (gold only).
__device__ __forceinline__ float dpp_add_xor1(float x) {      // [1,0,3,2]
    int y = __builtin_amdgcn_mov_dpp(__float_as_int(x), 0xB1, 0xF, 0xF, false);
    return x + __int_as_float(y);
}
__device__ __forceinline__ float dpp_add_xor2(float x) {      // [2,3,0,1]
    int y = __builtin_amdgcn_mov_dpp(__float_as_int(x), 0x4E, 0xF, 0xF, false);
    return x + __int_as_float(y);
}

__device__ __forceinline__ f32x4 exp4(f32x4 v) {
    f32x4 r;
    r.x = __expf(v.x); r.y = __expf(v.y); r.z = __expf(v.z); r.w = __expf(v.w);
    return r;
}
__device__ __forceinline__ float hsum4(f32x4 v) {
    return (v.x + v.y) + (v.z + v.w);
}

// ---------------------------------------------------------------------------
// FWD block body: ONE WAVE per chain -- the barrier is the bottleneck
// (R0/R2/R3/R4 all fit step = issue + LDS + ~550cyc barrier const).
// Lane: h = lane>>5 row-half (rows 64h..64h+63), c = lane&31 -> cols 4c..4c+3.
//   E fragment EH[k][cc].s = exp(trans[64h+4k+s][4c+cc]) = 256 VGPR
//   (<=512/wave at 1 wave/SIMD; no spill through ~450).
// Per step: 16 ds_read_b128 of the alpha half (2 addrs/wave -> 2-way
// broadcast = free), 64 f32x4 FMA, hsum4, ONE permlane32_swap cross-half
// add (VALU), eh mul, half-wave ds_write_b128, s_waitcnt lgkmcnt(0).
// NO s_barrier, no DPP tree, no leader, no partsA (csum from the same reads).
// ---------------------------------------------------------------------------
__device__ __forceinline__ void fwd_block(
    const int b, const int tid,
    const float* __restrict__ em, const float* __restrict__ mask,
    const float* __restrict__ startT, const float* __restrict__ endT,
    const float* __restrict__ trans, float* __restrict__ ws)
{
    __shared__ __align__(16) float Ab[2][CRF_T];

    const int h  = tid >> 5;          // row half
    const int c  = tid & 31;          // col quad
    const int j0 = 4 * c;

    // EH[k][cc].s = exp(trans[64h + 4k + s][j0+cc])   (256 VGPR)
    f32x4 EH[16][4];
#pragma unroll
    for (int k = 0; k < 16; ++k) {
#pragma unroll
        for (int s = 0; s < 4; ++s) {
            const int row = 64 * h + 4 * k + s;
            f32x4 t4 = *(const f32x4*)&trans[row * CRF_T + j0];
            EH[k][0][s] = __expf(t4.x);
            EH[k][1][s] = __expf(t4.y);
            EH[k][2][s] = __expf(t4.z);
            EH[k][3][s] = __expf(t4.w);
        }
    }

    const float* emb = em + (size_t)b * CRF_S * CRF_T + j0;
    const float mlast = mask[(size_t)b * CRF_S + (CRF_S - 1)];

    float logZ = 0.f;   // wave-uniform
    float rc = 1.f;     // wave-uniform
    f32x4 aout = {0.f, 0.f, 0.f, 0.f};

    // em pipeline: eh[cur] in use, eh[nxt] built this group; emv = group g+2.
    f32x4 emv[4], eh[2][4];
#pragma unroll
    for (int k = 0; k < 4; ++k) emv[k] = *(const f32x4*)(emb + (size_t)k * CRF_T);
#pragma unroll
    for (int k = 0; k < 4; ++k) eh[0][k] = exp4(emv[k]);
#pragma unroll
    for (int k = 0; k < 4; ++k) emv[k] = *(const f32x4*)(emb + (size_t)(4 + k) * CRF_T);

    auto STEP = [&](int t, int role, f32x4 ehv) {
        const int rb = (t & 1) ^ 1, wb = t & 1;

        wait_lds();   // prev step's write visible (same wave -> no barrier)

        const f32x4* A4 = (const f32x4*)&Ab[rb][64 * h];
        f32x4 av[16];
#pragma unroll
        for (int k = 0; k < 16; ++k) av[k] = A4[k];

        // rescale bookkeeping off the same reads (every lane, uniform).
        // t==1023's rescale is never applied -> must NOT enter logZ.
        if (role == 3 && t < 1023) {
            f32x4 cs = ((av[0] + av[1]) + (av[2] + av[3])) +
                       ((av[4] + av[5]) + (av[6] + av[7]));
            cs += ((av[8] + av[9]) + (av[10] + av[11])) +
                  ((av[12] + av[13]) + (av[14] + av[15]));
            float ch = hsum4(cs);          // this half's sum of alpha_{t-1}
            float cfull = xhalf_sum(ch);   // both halves, all lanes
            rc = __builtin_amdgcn_rcpf(cfull);
            logZ += __logf(cfull);
        }

        f32x4 ac0 = av[0] * EH[0][0];
        f32x4 ac1 = av[0] * EH[0][1];
        f32x4 ac2 = av[0] * EH[0][2];
        f32x4 ac3 = av[0] * EH[0][3];
#pragma unroll
        for (int k = 1; k < 16; ++k) {
            ac0 = __builtin_elementwise_fma(av[k], EH[k][0], ac0);
            ac1 = __builtin_elementwise_fma(av[k], EH[k][1], ac1);
            ac2 = __builtin_elementwise_fma(av[k], EH[k][2], ac2);
            ac3 = __builtin_elementwise_fma(av[k], EH[k][3], ac3);
        }
        // cross-half combine: d = own-half partial + other half's (VALU).
        float d0 = xhalf_sum(hsum4(ac0));
        float d1 = xhalf_sum(hsum4(ac1));
        float d2 = xhalf_sum(hsum4(ac2));
        float d3 = xhalf_sum(hsum4(ac3));

        f32x4 a4;
        a4.x = d0 * ehv.x; a4.y = d1 * ehv.y;
        a4.z = d2 * ehv.z; a4.w = d3 * ehv.w;
        if (role == 0) { a4.x *= rc; a4.y *= rc; a4.z *= rc; a4.w *= rc; }
        if (h == 0)
            *(f32x4*)&Ab[wb][j0] = a4;
        aout = a4;
    };

    // ---- group 0: t=0 init + steps 1..3 ----
    {
        f32x4 s4 = *(const f32x4*)&startT[j0];
        f32x4 a;
        a.x = __expf(s4.x) * eh[0][0].x;
        a.y = __expf(s4.y) * eh[0][0].y;
        a.z = __expf(s4.z) * eh[0][0].z;
        a.w = __expf(s4.w) * eh[0][0].w;
        if (h == 0)
            *(f32x4*)&Ab[0][j0] = a;
        aout = a;
        STEP(1, 1, eh[0][1]);
#pragma unroll
        for (int k = 0; k < 4; ++k) eh[1][k] = exp4(emv[k]);   // group 1
        STEP(2, 2, eh[0][2]);
#pragma unroll
        for (int k = 0; k < 4; ++k) emv[k] = *(const f32x4*)(emb + (size_t)(8 + k) * CRF_T); // group 2
        STEP(3, 3, eh[0][3]);
    }

    // ---- groups 1..255 ----
#pragma unroll 1
    for (int g = 1; g < 256; ++g) {
        const int t0 = 4 * g;
        const int cur = g & 1, nxt = cur ^ 1;
        STEP(t0 + 0, 0, eh[cur][0]);
        STEP(t0 + 1, 1, eh[cur][1]);
        if (g <= 254) {
#pragma unroll
            for (int k = 0; k < 4; ++k) eh[nxt][k] = exp4(emv[k]);  // group g+1
        }
        STEP(t0 + 2, 2, eh[cur][2]);
        if (g <= 253) {
#pragma unroll
            for (int k = 0; k < 4; ++k)
                emv[k] = *(const f32x4*)(emb + (size_t)(t0 + 8 + k) * CRF_T); // group g+2
        }
        STEP(t0 + 3, 3, eh[cur][3]);
    }

    // ---- finale: alpha_1023 in aout (this lane's 4 cols, dup across halves)
    f32x4 v4;
    v4.x = (__logf(aout.x) + logZ) * mlast + endT[j0 + 0];
    v4.y = (__logf(aout.y) + logZ) * mlast + endT[j0 + 1];
    v4.z = (__logf(aout.z) + logZ) * mlast + endT[j0 + 2];
    v4.w = (__logf(aout.w) + logZ) * mlast + endT[j0 + 3];
    float mx = fmaxf(fmaxf(v4.x, v4.y), fmaxf(v4.z, v4.w));
#pragma unroll
    for (int d = 1; d < 64; d <<= 1) mx = fmaxf(mx, __shfl_xor(mx, d));
    // halves duplicate the 128 cols -> count each col once (h==0 only).
    float ex = 0.f;
    if (h == 0)
        ex = __expf(v4.x - mx) + __expf(v4.y - mx) +
             __expf(v4.z - mx) + __expf(v4.w - mx);
#pragma unroll
    for (int d = 1; d < 64; d <<= 1) ex += __shfl_xor(ex, d);
    if (tid == 0)
        ws[WS_FWD + b] = mx + __logf(ex);
}

// ---------------------------------------------------------------------------
// GOLD block body (128 threads): tag-gather (negated) + S2 for a 128-row
// slice. Partial to ws[gb]. Runs concurrently with fwd blocks, filling the
// idle SIMDs of the latency-bound chains. (Unchanged from R4 -- verified.)
// ---------------------------------------------------------------------------
__device__ __forceinline__ void gold_block(
    const int gb, const int tid,
    const float* __restrict__ em, const int* __restrict__ tags,
    const float* __restrict__ mask, const float* __restrict__ startT,
    const float* __restrict__ endT, const float* __restrict__ trans,
    float* __restrict__ ws)
{
    const int b     = gb >> 3;                    // GSPLIT == 8
    const int slice = gb & (GSPLIT - 1);
    const int base  = slice << 7;                 // 128 rows per slice
    const int p = tid & 3;      // quad member
    const int q = tid >> 2;     // quad id 0..31
    const int* tg = tags + (size_t)b * CRF_S;
    const float* mk = mask + (size_t)b * CRF_S;
    const float* emr = em + (size_t)b * CRF_S * CRF_T;

    __shared__ float r2g[2];

    // ---- tag-gather: one t per thread ----
    float g_acc = 0.f;
    {
        const int t = base + tid;
        const int tagt = tg[t];
        const float m = mk[t];
        g_acc += emr[(size_t)t * CRF_T + tagt] * m;
        if (t >= 1) g_acc += trans[tg[t - 1] * CRF_T + tagt] * m;
    }
    if (tid == 0 && slice == 0)
        g_acc += startT[tg[0]];
    if (tid == 0 && slice == GSPLIT - 1)
        g_acc += endT[tg[CRF_S - 1]] * mk[CRF_S - 1];

    // ---- S2: quad q handles rows base+q+32*it; lane p cols 4p+16k ----
    float s2 = 0.f;
#pragma unroll
    for (int it = 0; it < 4; ++it) {
        const int rr = base + it * 32 + q;
        const float* row = emr + (size_t)rr * CRF_T;
        f32x4 sum4 = {0.f, 0.f, 0.f, 0.f};
#pragma unroll
        for (int k = 0; k < 8; ++k)
            sum4 += exp4(*(const f32x4*)(row + k * 16 + p * 4));
        float s = hsum4(sum4);
        s = dpp_add_xor1(s);
        s = dpp_add_xor2(s);
        if (p == 0) s2 += __logf(s) * mk[rr];
    }

    float contrib = s2 - g_acc;
#pragma unroll
    for (int d = 1; d < 64; d <<= 1) contrib += __shfl_xor(contrib, d);
    if ((tid & 63) == 0) r2g[tid >> 6] = contrib;
    __syncthreads();
    if (tid == 0)
        ws[gb] = r2g[0] + r2g[1];
}

// ---------------------------------------------------------------------------
// Fused kernel: blocks [0,NFWD) = fwd chains (single wave; tid>=64 exits);
// blocks [NFWD, NFWD+NGOLD) = gold slices filling the remaining capacity.
// ---------------------------------------------------------------------------
__global__ __launch_bounds__(128, 1) void crf_main_kernel(
    const float* __restrict__ em, const int* __restrict__ tags,
    const float* __restrict__ mask, const float* __restrict__ startT,
    const float* __restrict__ endT, const float* __restrict__ trans,
    float* __restrict__ ws)
{
    if (blockIdx.x < NFWD) {
        if (threadIdx.x >= 64) return;   // one wave; no __syncthreads in path
        fwd_block(blockIdx.x, threadIdx.x, em, mask, startT, endT, trans, ws);
    } else {
        gold_block(blockIdx.x - NFWD, threadIdx.x, em, tags, mask, startT,
                   endT, trans, ws);
    }
}

// ---------------------------------------------------------------------------
// Reduce: sum the 2304 ws partials (2048 gold, negated + 256 fwd), /B.
// ---------------------------------------------------------------------------
__global__ __launch_bounds__(256) void crf_reduce_kernel(
    const float* __restrict__ ws, float* __restrict__ out)
{
    const int tid = threadIdx.x;
    float s = 0.f;
#pragma unroll
    for (int k = 0; k < WS_N; k += 256) s += ws[k + tid];   // WS_N = 9*256
#pragma unroll
    for (int d = 1; d < 64; d <<= 1) s += __shfl_xor(s, d);
    __shared__ float r4[4];
    if ((tid & 63) == 0) r4[tid >> 6] = s;
    __syncthreads();
    if (tid == 0)
        out[0] = ((r4[0] + r4[1]) + (r4[2] + r4[3])) * (1.0f / CRF_B);
}

// ---------------------------------------------------------------------------
extern "C" void kernel_launch(void* const* d_in, const int* in_sizes, int n_in,
                              void* d_out, int out_size, void* d_ws, size_t ws_size,
                              hipStream_t stream)
{
    const float* em     = (const float*)d_in[0];
    const int*   tags   = (const int*)d_in[1];
    const float* mask   = (const float*)d_in[2];
    const float* startT = (const float*)d_in[3];
    const float* endT   = (const float*)d_in[4];
    const float* trans  = (const float*)d_in[5];
    float* out = (float*)d_out;
    float* ws  = (float*)d_ws;

    hipLaunchKernelGGL(crf_main_kernel, dim3(NFWD + NGOLD), dim3(128), 0, stream,
                       em, tags, mask, startT, endT, trans, ws);
    hipLaunchKernelGGL(crf_reduce_kernel, dim3(1), dim3(256), 0, stream,
                       ws, out);
}

// Round 7
// 689.220 us; speedup vs baseline: 1.5782x; 1.5782x over previous
//
#include <hip/hip_runtime.h>

#define CRF_B 256
#define CRF_S 1024
#define CRF_T 128
#define GSPLIT 8                     // gold: S-slices per batch (128 rows each)
#define NFWD   CRF_B                 // fused grid: blocks [0,256) = fwd chains
#define NGOLD  (CRF_B * GSPLIT)      // blocks [256,2304) = gold slices
#define NBLK   (NFWD + NGOLD)        // 2304
#define WS_FWD (CRF_B * GSPLIT)      // ws: [0,2048) gold partials,
#define WS_N   (WS_FWD + CRF_B)      //     [2048,2304) fwd results; [2304]=cnt

typedef __attribute__((ext_vector_type(4))) float f32x4;

// Barrier that waits only on LDS ops (lgkmcnt), NOT vmcnt: keeps global
// em-prefetch loads in flight across steps (__syncthreads drains vmcnt(0)).
__device__ __forceinline__ void barrier_lds_only() {
    __asm__ volatile("s_waitcnt lgkmcnt(0)\n\ts_barrier" ::: "memory");
}

// Cross-lane butterfly adds on the VALU pipe (DPP), no LDS/bpermute.
__device__ __forceinline__ float dpp_add_xor1(float x) {      // quad_perm [1,0,3,2]
    int y = __builtin_amdgcn_mov_dpp(__float_as_int(x), 0xB1, 0xF, 0xF, false);
    return x + __int_as_float(y);
}
__device__ __forceinline__ float dpp_add_xor2(float x) {      // quad_perm [2,3,0,1]
    int y = __builtin_amdgcn_mov_dpp(__float_as_int(x), 0x4E, 0xF, 0xF, false);
    return x + __int_as_float(y);
}
// After xor1+xor2 the value is quad-uniform, so ROW_HALF_MIRROR (lane^7 within
// 8) acts as xor4: combines the two quads of each 8-lane row group.
__device__ __forceinline__ float dpp_add_xor4u(float x) {     // ROW_HALF_MIRROR
    int y = __builtin_amdgcn_mov_dpp(__float_as_int(x), 0x141, 0xF, 0xF, false);
    return x + __int_as_float(y);
}

__device__ __forceinline__ f32x4 exp4(f32x4 v) {
    f32x4 r;
    r.x = __expf(v.x); r.y = __expf(v.y); r.z = __expf(v.z); r.w = __expf(v.w);
    return r;
}
__device__ __forceinline__ float hsum4(f32x4 v) {
    return (v.x + v.y) + (v.z + v.w);
}

// ---------------------------------------------------------------------------
// FWD block body: R0's verified 4-wave structure (1017 cyc/step, best of 5
// measured structures). r = tid&7 row group, cq = tid>>3 col quad, E 16x4
// tile in regs (64 VGPR), swizzled ds_read_b128, 3-stage DPP reduce, leader
// write, lgkm-only barrier, lazy rescale every 4 steps.
// R6/R7 change: the eh-exp4/em-prefetch "filler" executes INSIDE STEP,
// between ds_read issue and FMA consume, so the ~120cy LDS read latency is
// covered by independent work instead of delaying the reads.
// ---------------------------------------------------------------------------
__device__ __forceinline__ void fwd_block(
    const int b, const int tid,
    const float* __restrict__ em, const float* __restrict__ mask,
    const float* __restrict__ startT, const float* __restrict__ endT,
    const float* __restrict__ trans, float* __restrict__ ws)
{
    const int r = tid & 7;       // row group: rows r*16 .. r*16+15
    const int cq = tid >> 3;     // 0..31
    const int j0 = cq * 4;
    const bool leader = (r == 0);

    __shared__ __align__(16) float Abuf[2][CRF_T];
    __shared__ __align__(16) float partsA[32];
    __shared__ float red[8];
    __shared__ float lzsh;

    // k-swizzle: thread's 4 b128 reads at float-idx r*16 + ((k+r)&3)*4.
    int kidx[4];
#pragma unroll
    for (int k = 0; k < 4; ++k) kidx[k] = (k + r) & 3;

    // EE[k][c][s] = exp(trans[i][j0+c]), i = r*16 + kidx[k]*4 + s  (64 VGPRs)
    f32x4 EE[4][4];
#pragma unroll
    for (int k = 0; k < 4; ++k) {
#pragma unroll
        for (int s = 0; s < 4; ++s) {
            const int i = r * 16 + kidx[k] * 4 + s;
            f32x4 t4 = *(const f32x4*)&trans[i * CRF_T + j0];
            EE[k][0][s] = __expf(t4.x);
            EE[k][1][s] = __expf(t4.y);
            EE[k][2][s] = __expf(t4.z);
            EE[k][3][s] = __expf(t4.w);
        }
    }

    const float* emb = em + (size_t)b * CRF_S * CRF_T + j0;
    const float mlast = mask[(size_t)b * CRF_S + (CRF_S - 1)];

    float logZ = 0.f;   // leaders only
    float rc = 1.f;     // leaders only (non-leader alpha is never written)

    // em pipeline: eh[cur] in use, eh[nxt] built this group; emv = group g+2.
    f32x4 emv[4], eh[2][4];
#pragma unroll
    for (int k = 0; k < 4; ++k) emv[k] = *(const f32x4*)(emb + (size_t)k * CRF_T);
#pragma unroll
    for (int k = 0; k < 4; ++k) eh[0][k] = exp4(emv[k]);
#pragma unroll
    for (int k = 0; k < 4; ++k) emv[k] = *(const f32x4*)(emb + (size_t)(4 + k) * CRF_T);

    auto STEP = [&](int t, int role, f32x4 ehv, auto&& filler) {
        const int rb = (t & 1) ^ 1, wb = t & 1;

        // Issue the alpha reads FIRST (right after the previous barrier)...
        const f32x4* A4 = (const f32x4*)&Abuf[rb][r * 16];
        f32x4 av[4];
#pragma unroll
        for (int k = 0; k < 4; ++k) av[k] = A4[kidx[k]];

        // ...then independent filler work (exp4 / prefetch) hides their latency.
        filler();

        // t==1023's rescale is never applied -> must NOT enter logZ.
        if (role == 3 && leader && t < 1023) {
            const f32x4* pa = (const f32x4*)partsA;   // csum written at t-1
            f32x4 s8 = ((pa[0] + pa[1]) + (pa[2] + pa[3])) +
                       ((pa[4] + pa[5]) + (pa[6] + pa[7]));
            float c = hsum4(s8);
            rc = __builtin_amdgcn_rcpf(c);
            logZ += __logf(c);
        }

        f32x4 ac0 = av[0] * EE[0][0];
        f32x4 ac1 = av[0] * EE[0][1];
        f32x4 ac2 = av[0] * EE[0][2];
        f32x4 ac3 = av[0] * EE[0][3];
#pragma unroll
        for (int k = 1; k < 4; ++k) {
            ac0 = __builtin_elementwise_fma(av[k], EE[k][0], ac0);
            ac1 = __builtin_elementwise_fma(av[k], EE[k][1], ac1);
            ac2 = __builtin_elementwise_fma(av[k], EE[k][2], ac2);
            ac3 = __builtin_elementwise_fma(av[k], EE[k][3], ac3);
        }
        float d0 = hsum4(ac0), d1 = hsum4(ac1), d2 = hsum4(ac2), d3 = hsum4(ac3);
        d0 = dpp_add_xor4u(dpp_add_xor2(dpp_add_xor1(d0)));
        d1 = dpp_add_xor4u(dpp_add_xor2(dpp_add_xor1(d1)));
        d2 = dpp_add_xor4u(dpp_add_xor2(dpp_add_xor1(d2)));
        d3 = dpp_add_xor4u(dpp_add_xor2(dpp_add_xor1(d3)));

        float a0 = d0 * ehv.x, a1 = d1 * ehv.y, a2 = d2 * ehv.z, a3 = d3 * ehv.w;
        if (role == 0) { a0 *= rc; a1 *= rc; a2 *= rc; a3 *= rc; }
        if (leader) {
            f32x4 avw = {a0, a1, a2, a3};
            *(f32x4*)&Abuf[wb][j0] = avw;
            if (role == 2) partsA[cq] = (a0 + a1) + (a2 + a3);
        }
        barrier_lds_only();
    };

    auto NOFILL = [] {};

    // ---- group 0: t=0 init + steps 1..3 ----
    {
        f32x4 s4 = *(const f32x4*)&startT[j0];
        if (leader) {
            f32x4 a;
            a.x = __expf(s4.x) * eh[0][0].x;
            a.y = __expf(s4.y) * eh[0][0].y;
            a.z = __expf(s4.z) * eh[0][0].z;
            a.w = __expf(s4.w) * eh[0][0].w;
            *(f32x4*)&Abuf[0][j0] = a;
        }
        barrier_lds_only();
        STEP(1, 1, eh[0][1], NOFILL);
        STEP(2, 2, eh[0][2], [&] {
#pragma unroll
            for (int k = 0; k < 4; ++k) eh[1][k] = exp4(emv[k]);   // group 1
        });
        STEP(3, 3, eh[0][3], [&] {
#pragma unroll
            for (int k = 0; k < 4; ++k)
                emv[k] = *(const f32x4*)(emb + (size_t)(8 + k) * CRF_T); // group 2
        });
    }

    // ---- groups 1..255 ----
#pragma unroll 1
    for (int g = 1; g < 256; ++g) {
        const int t0 = 4 * g;
        const int cur = g & 1, nxt = cur ^ 1;
        STEP(t0 + 0, 0, eh[cur][0], NOFILL);
        STEP(t0 + 1, 1, eh[cur][1], NOFILL);
        STEP(t0 + 2, 2, eh[cur][2], [&] {
            if (g <= 254) {
#pragma unroll
                for (int k = 0; k < 4; ++k) eh[nxt][k] = exp4(emv[k]); // group g+1
            }
        });
        STEP(t0 + 3, 3, eh[cur][3], [&] {
            if (g <= 253) {
#pragma unroll
                for (int k = 0; k < 4; ++k)
                    emv[k] = *(const f32x4*)(emb + (size_t)(t0 + 8 + k) * CRF_T); // g+2
            }
        });
    }

    // ---- finale: A~_1023 in Abuf[1]; logZ in leader lanes ----
    __syncthreads();
    if (tid == 0) lzsh = logZ;
    __syncthreads();
    const float lz = lzsh;

    float v = -3.0e38f;
    if (tid < 128)
        v = (__logf(Abuf[1][tid]) + lz) * mlast + endT[tid];
    float mx = v;
#pragma unroll
    for (int dd = 1; dd < 64; dd <<= 1) mx = fmaxf(mx, __shfl_xor(mx, dd));
    if ((tid & 63) == 0) red[tid >> 6] = mx;
    __syncthreads();
    mx = fmaxf(fmaxf(red[0], red[1]), fmaxf(red[2], red[3]));
    float ex = (tid < 128) ? __expf(v - mx) : 0.f;
#pragma unroll
    for (int dd = 1; dd < 64; dd <<= 1) ex += __shfl_xor(ex, dd);
    if ((tid & 63) == 0) red[4 + (tid >> 6)] = ex;
    __syncthreads();
    if (tid == 0)
        ws[WS_FWD + b] = mx + __logf((red[4] + red[5]) + (red[6] + red[7]));
}

// ---------------------------------------------------------------------------
// GOLD block body (256 threads): tag-gather (negated) + S2 for a 128-row
// slice. Partial to ws[gb]. Runs concurrently with fwd blocks (same launch),
// filling the idle SIMD slots of the latency-bound chains. (R2/R4-verified.)
// ---------------------------------------------------------------------------
__device__ __forceinline__ void gold_block(
    const int gb, const int tid,
    const float* __restrict__ em, const int* __restrict__ tags,
    const float* __restrict__ mask, const float* __restrict__ startT,
    const float* __restrict__ endT, const float* __restrict__ trans,
    float* __restrict__ ws)
{
    const int b     = gb >> 3;                    // GSPLIT == 8
    const int slice = gb & (GSPLIT - 1);
    const int base  = slice << 7;                 // 128 rows per slice
    const int p = tid & 3;      // quad member
    const int q = tid >> 2;     // quad id 0..63
    const int* tg = tags + (size_t)b * CRF_S;
    const float* mk = mask + (size_t)b * CRF_S;
    const float* emr = em + (size_t)b * CRF_S * CRF_T;

    __shared__ float r4g[4];

    // ---- tag-gather: one t per thread (tid<128) ----
    float g_acc = 0.f;
    if (tid < 128) {
        const int t = base + tid;
        const int tagt = tg[t];
        const float m = mk[t];
        g_acc += emr[(size_t)t * CRF_T + tagt] * m;
        if (t >= 1) g_acc += trans[tg[t - 1] * CRF_T + tagt] * m;
    }
    if (tid == 0 && slice == 0)
        g_acc += startT[tg[0]];
    if (tid == 0 && slice == GSPLIT - 1)
        g_acc += endT[tg[CRF_S - 1]] * mk[CRF_S - 1];

    // ---- S2: quad q handles rows base+q, base+q+64; lane p cols 4p+16k ----
    float s2 = 0.f;
#pragma unroll
    for (int it = 0; it < 2; ++it) {
        const int rr = base + it * 64 + q;
        const float* row = emr + (size_t)rr * CRF_T;
        f32x4 sum4 = {0.f, 0.f, 0.f, 0.f};
#pragma unroll
        for (int k = 0; k < 8; ++k)
            sum4 += exp4(*(const f32x4*)(row + k * 16 + p * 4));
        float s = hsum4(sum4);
        s = dpp_add_xor1(s);
        s = dpp_add_xor2(s);
        if (p == 0) s2 += __logf(s) * mk[rr];
    }

    float contrib = s2 - g_acc;
#pragma unroll
    for (int d = 1; d < 64; d <<= 1) contrib += __shfl_xor(contrib, d);
    if ((tid & 63) == 0) r4g[tid >> 6] = contrib;
    __syncthreads();
    if (tid == 0)
        ws[gb] = (r4g[0] + r4g[1]) + (r4g[2] + r4g[3]);
}

// ---------------------------------------------------------------------------
// Last-done block performs the final reduce. Counter at ws[WS_N] is ZEROED by
// a 4-byte hipMemsetAsync before every launch (R6 bug: "works for any initial
// value" fails when garbage init makes the 2304 increments straddle the
// unsigned wrap -- 2^32 % 2304 = 256 != 0 -> zero/two finishers).
// ---------------------------------------------------------------------------
__device__ __forceinline__ void finish_and_reduce(
    float* __restrict__ ws, float* __restrict__ out, const int tid)
{
    __shared__ unsigned osh;
    __shared__ float r4f[4];
    __threadfence();                       // release ws write
    if (tid == 0)
        osh = atomicAdd((unsigned*)(ws + WS_N), 1u);
    __syncthreads();
    if (osh != (unsigned)(NBLK - 1)) return;   // block-uniform
    __threadfence();                       // acquire all ws writes

    float s = 0.f;
#pragma unroll
    for (int k = 0; k < WS_N; k += 256) s += ws[k + tid];   // WS_N = 9*256
#pragma unroll
    for (int d = 1; d < 64; d <<= 1) s += __shfl_xor(s, d);
    if ((tid & 63) == 0) r4f[tid >> 6] = s;
    __syncthreads();
    if (tid == 0)
        out[0] = ((r4f[0] + r4f[1]) + (r4f[2] + r4f[3])) * (1.0f / CRF_B);
}

// ---------------------------------------------------------------------------
// Fused kernel: blocks [0,NFWD) = fwd chains (dispatched first, ~1 per CU);
// blocks [NFWD, NBLK) = gold slices filling remaining capacity; last-done
// block reduces.
// ---------------------------------------------------------------------------
__global__ __launch_bounds__(256) void crf_main_kernel(
    const float* __restrict__ em, const int* __restrict__ tags,
    const float* __restrict__ mask, const float* __restrict__ startT,
    const float* __restrict__ endT, const float* __restrict__ trans,
    float* __restrict__ ws, float* __restrict__ out)
{
    if (blockIdx.x < NFWD)
        fwd_block(blockIdx.x, threadIdx.x, em, mask, startT, endT, trans, ws);
    else
        gold_block(blockIdx.x - NFWD, threadIdx.x, em, tags, mask, startT,
                   endT, trans, ws);
    finish_and_reduce(ws, out, threadIdx.x);
}

// ---------------------------------------------------------------------------
extern "C" void kernel_launch(void* const* d_in, const int* in_sizes, int n_in,
                              void* d_out, int out_size, void* d_ws, size_t ws_size,
                              hipStream_t stream)
{
    const float* em     = (const float*)d_in[0];
    const int*   tags   = (const int*)d_in[1];
    const float* mask   = (const float*)d_in[2];
    const float* startT = (const float*)d_in[3];
    const float* endT   = (const float*)d_in[4];
    const float* trans  = (const float*)d_in[5];
    float* out = (float*)d_out;
    float* ws  = (float*)d_ws;

    // Zero the finisher counter (4 bytes) each launch; same-stream ordering
    // guarantees it precedes the kernel. Graph-capture-legal (async).
    hipMemsetAsync((void*)(ws + WS_N), 0, sizeof(unsigned), stream);
    hipLaunchKernelGGL(crf_main_kernel, dim3(NBLK), dim3(256), 0, stream,
                       em, tags, mask, startT, endT, trans, ws, out);
}